// Round 2
// baseline (715.418 us; speedup 1.0000x reference)
//
#include <hip/hip_runtime.h>
#include <math.h>

#define BATCH 16384
#define HIDDEN 2048
#define NOUT 256

static constexpr float PHI_SCALE = 0.08838834764831845f;  // sqrt(2/256)

// ---------------------------------------------------------------------------
// Kernel A: Phi = PHI_SCALE * cos(x @ W^T - b)   (cos is even: cos(-d+b)=cos(d-b))
// Also emits s_row[b] = sum_o Phi[b][o].
// Tile: 64 rows x 256 cols, BK=16, 256 threads, 4x16 micro-tile per thread.
// ---------------------------------------------------------------------------
__global__ __launch_bounds__(256) void phi_kernel(
    const float* __restrict__ x, const float* __restrict__ W,
    const float* __restrict__ bvec, float* __restrict__ Phi,
    float* __restrict__ s_row)
{
  __shared__ float xs[16][68];    // [k][row], padded (68*4=272B, 16B-aligned rows)
  __shared__ float wsh[16][260];  // [k][col], padded (260*4=1040B, 16B-aligned rows)

  const int tid = threadIdx.x;
  const int tx = tid & 15;        // col group: cols tx*4 + g*64 + j
  const int ty = tid >> 4;        // row group: rows ty*4 + i
  const int m0 = blockIdx.x * 64;
  const int lr = tid >> 2;        // staging row 0..63
  const int lk = (tid & 3) * 4;   // staging k offset 0,4,8,12

  float acc[4][16];
#pragma unroll
  for (int i = 0; i < 4; i++)
#pragma unroll
    for (int c = 0; c < 16; c++) acc[i][c] = 0.f;

  // prefetch first tile
  float4 xv  = *(const float4*)&x[(size_t)(m0 + lr) * HIDDEN + lk];
  float4 wv0 = *(const float4*)&W[(size_t)(lr      ) * HIDDEN + lk];
  float4 wv1 = *(const float4*)&W[(size_t)(lr +  64) * HIDDEN + lk];
  float4 wv2 = *(const float4*)&W[(size_t)(lr + 128) * HIDDEN + lk];
  float4 wv3 = *(const float4*)&W[(size_t)(lr + 192) * HIDDEN + lk];

  for (int kb = 0; kb < HIDDEN; kb += 16) {
    __syncthreads();
    {
      const float* xp = (const float*)&xv;
      const float* w0 = (const float*)&wv0;
      const float* w1 = (const float*)&wv1;
      const float* w2 = (const float*)&wv2;
      const float* w3 = (const float*)&wv3;
#pragma unroll
      for (int j = 0; j < 4; j++) {
        xs[lk + j][lr]        = xp[j];
        wsh[lk + j][lr]       = w0[j];
        wsh[lk + j][lr +  64] = w1[j];
        wsh[lk + j][lr + 128] = w2[j];
        wsh[lk + j][lr + 192] = w3[j];
      }
    }
    __syncthreads();
    // prefetch next tile (issues before the long compute; latency hidden)
    if (kb + 16 < HIDDEN) {
      xv  = *(const float4*)&x[(size_t)(m0 + lr) * HIDDEN + kb + 16 + lk];
      wv0 = *(const float4*)&W[(size_t)(lr      ) * HIDDEN + kb + 16 + lk];
      wv1 = *(const float4*)&W[(size_t)(lr +  64) * HIDDEN + kb + 16 + lk];
      wv2 = *(const float4*)&W[(size_t)(lr + 128) * HIDDEN + kb + 16 + lk];
      wv3 = *(const float4*)&W[(size_t)(lr + 192) * HIDDEN + kb + 16 + lk];
    }
#pragma unroll
    for (int k = 0; k < 16; k++) {
      const float4 a = *(const float4*)&xs[k][ty * 4];
      const float* ap = (const float*)&a;
#pragma unroll
      for (int g = 0; g < 4; g++) {
        const float4 bb = *(const float4*)&wsh[k][tx * 4 + g * 64];
        const float* bp = (const float*)&bb;
#pragma unroll
        for (int i = 0; i < 4; i++)
#pragma unroll
          for (int j = 0; j < 4; j++)
            acc[i][g * 4 + j] = fmaf(ap[i], bp[j], acc[i][g * 4 + j]);
      }
    }
  }

  // epilogue: cos, Phi store, row-sum
  float rs[4] = {0.f, 0.f, 0.f, 0.f};
#pragma unroll
  for (int g = 0; g < 4; g++) {
    const int cbase = g * 64 + tx * 4;
    const float4 bb = *(const float4*)&bvec[cbase];
    const float* bp = (const float*)&bb;
#pragma unroll
    for (int i = 0; i < 4; i++) {
      float4 ph;
      float* pp = (float*)&ph;
#pragma unroll
      for (int j = 0; j < 4; j++) {
        pp[j] = PHI_SCALE * cosf(acc[i][g * 4 + j] - bp[j]);
        rs[i] += pp[j];
      }
      *(float4*)&Phi[(size_t)(m0 + ty * 4 + i) * NOUT + cbase] = ph;
    }
  }
#pragma unroll
  for (int i = 0; i < 4; i++) {
    float v = rs[i];
#pragma unroll
    for (int m = 1; m < 16; m <<= 1) v += __shfl_xor(v, m);
    if (tx == 0) s_row[m0 + ty * 4 + i] = v;
  }
}

// ---------------------------------------------------------------------------
// Kernel B: out = Phi @ Beta; softmax per row; scalars[k] += sum_b w[b,k]*s2[b]
// Same 64x256 tiling over K=256.
// ---------------------------------------------------------------------------
__global__ __launch_bounds__(256) void out_kernel(
    const float* __restrict__ Phi, const float* __restrict__ Beta,
    const float* __restrict__ s_row, float* __restrict__ out,
    float* __restrict__ scalars)
{
  __shared__ float ps[16][68];
  __shared__ float bs[16][260];
  __shared__ float sb[NOUT];

  const int tid = threadIdx.x;
  const int tx = tid & 15;
  const int ty = tid >> 4;
  const int m0 = blockIdx.x * 64;
  const int lr = tid >> 2;
  const int lk = (tid & 3) * 4;
  const int bkr = tid >> 4;         // Beta staging k-row 0..15
  const int bc = (tid & 15) * 16;   // Beta staging col base

  sb[tid] = 0.f;

  float acc[4][16];
#pragma unroll
  for (int i = 0; i < 4; i++)
#pragma unroll
    for (int c = 0; c < 16; c++) acc[i][c] = 0.f;

  float4 pv  = *(const float4*)&Phi[(size_t)(m0 + lr) * NOUT + lk];
  float4 bv0 = *(const float4*)&Beta[(size_t)bkr * NOUT + bc];
  float4 bv1 = *(const float4*)&Beta[(size_t)bkr * NOUT + bc + 4];
  float4 bv2 = *(const float4*)&Beta[(size_t)bkr * NOUT + bc + 8];
  float4 bv3 = *(const float4*)&Beta[(size_t)bkr * NOUT + bc + 12];

  for (int kb = 0; kb < NOUT; kb += 16) {
    __syncthreads();
    {
      const float* pp = (const float*)&pv;
#pragma unroll
      for (int j = 0; j < 4; j++) ps[lk + j][lr] = pp[j];
      *(float4*)&bs[bkr][bc]      = bv0;
      *(float4*)&bs[bkr][bc + 4]  = bv1;
      *(float4*)&bs[bkr][bc + 8]  = bv2;
      *(float4*)&bs[bkr][bc + 12] = bv3;
    }
    __syncthreads();
    if (kb + 16 < NOUT) {
      pv  = *(const float4*)&Phi[(size_t)(m0 + lr) * NOUT + kb + 16 + lk];
      bv0 = *(const float4*)&Beta[(size_t)(kb + 16 + bkr) * NOUT + bc];
      bv1 = *(const float4*)&Beta[(size_t)(kb + 16 + bkr) * NOUT + bc + 4];
      bv2 = *(const float4*)&Beta[(size_t)(kb + 16 + bkr) * NOUT + bc + 8];
      bv3 = *(const float4*)&Beta[(size_t)(kb + 16 + bkr) * NOUT + bc + 12];
    }
#pragma unroll
    for (int k = 0; k < 16; k++) {
      const float4 a = *(const float4*)&ps[k][ty * 4];
      const float* ap = (const float*)&a;
#pragma unroll
      for (int g = 0; g < 4; g++) {
        const float4 bb = *(const float4*)&bs[k][tx * 4 + g * 64];
        const float* bp = (const float*)&bb;
#pragma unroll
        for (int i = 0; i < 4; i++)
#pragma unroll
          for (int j = 0; j < 4; j++)
            acc[i][g * 4 + j] = fmaf(ap[i], bp[j], acc[i][g * 4 + j]);
      }
    }
  }

  // write out
#pragma unroll
  for (int g = 0; g < 4; g++) {
    const int cbase = g * 64 + tx * 4;
#pragma unroll
    for (int i = 0; i < 4; i++) {
      float4 ov;
      ov.x = acc[i][g * 4 + 0]; ov.y = acc[i][g * 4 + 1];
      ov.z = acc[i][g * 4 + 2]; ov.w = acc[i][g * 4 + 3];
      *(float4*)&out[(size_t)(m0 + ty * 4 + i) * NOUT + cbase] = ov;
    }
  }

  // softmax + w*s2 class partials
  float cp[16];
#pragma unroll
  for (int c = 0; c < 16; c++) cp[c] = 0.f;

#pragma unroll
  for (int i = 0; i < 4; i++) {
    float mx = acc[i][0];
#pragma unroll
    for (int c = 1; c < 16; c++) mx = fmaxf(mx, acc[i][c]);
#pragma unroll
    for (int m = 1; m < 16; m <<= 1) mx = fmaxf(mx, __shfl_xor(mx, m));
    float e[16];
    float sum = 0.f;
#pragma unroll
    for (int c = 0; c < 16; c++) { e[c] = __expf(acc[i][c] - mx); sum += e[c]; }
#pragma unroll
    for (int m = 1; m < 16; m <<= 1) sum += __shfl_xor(sum, m);
    const float inv = 1.f / sum;
    float sv = s_row[m0 + ty * 4 + i];
    sv = sv * sv;
#pragma unroll
    for (int c = 0; c < 16; c++) {
      const float p = e[c] * inv;
      cp[c] = fmaf(p * (1.f - p), sv, cp[c]);
    }
  }
  // reduce across the 4 ty-groups within the wave (lane bits 4,5)
#pragma unroll
  for (int c = 0; c < 16; c++) {
    cp[c] += __shfl_xor(cp[c], 16);
    cp[c] += __shfl_xor(cp[c], 32);
  }
  if ((ty & 3) == 0) {
#pragma unroll
    for (int g = 0; g < 4; g++)
#pragma unroll
      for (int j = 0; j < 4; j++)
        atomicAdd(&sb[g * 64 + tx * 4 + j], cp[g * 4 + j]);
  }
  __syncthreads();
  atomicAdd(&scalars[tid], sb[tid]);
}

// ---------------------------------------------------------------------------
// Kernel C: sigma_new = 0.999*sigma + (0.001/65536)*scalars[k],  k = idx>>16
// ---------------------------------------------------------------------------
__global__ __launch_bounds__(256) void sigma_kernel(
    const float* __restrict__ sig, const float* __restrict__ scalars,
    float* __restrict__ so)
{
  const int total4 = (NOUT * NOUT * NOUT) / 4;
  const float cscale = 0.001f / 65536.f;
  for (int i = blockIdx.x * 256 + threadIdx.x; i < total4; i += gridDim.x * 256) {
    const float4 s = ((const float4*)sig)[i];
    const int k = i >> 14;  // 16384 float4 per class
    const float add = scalars[k] * cscale;
    float4 r;
    r.x = fmaf(0.999f, s.x, add);
    r.y = fmaf(0.999f, s.y, add);
    r.z = fmaf(0.999f, s.z, add);
    r.w = fmaf(0.999f, s.w, add);
    ((float4*)so)[i] = r;
  }
}

extern "C" void kernel_launch(void* const* d_in, const int* in_sizes, int n_in,
                              void* d_out, int out_size, void* d_ws, size_t ws_size,
                              hipStream_t stream)
{
  const float* x    = (const float*)d_in[0];
  const float* W    = (const float*)d_in[1];
  const float* bvec = (const float*)d_in[2];
  const float* Beta = (const float*)d_in[3];
  const float* sig  = (const float*)d_in[4];

  float* out = (float*)d_out;
  float* sigma_out = out + (size_t)BATCH * NOUT;  // second tuple element
  // Stage Phi in the sigma output region (16.8 MB < 67 MB); kernel C
  // overwrites it afterwards (stream-ordered).
  float* Phi = sigma_out;
  float* s_row   = (float*)d_ws;       // 16384 floats
  float* scalars = s_row + BATCH;      // 256 floats, accumulated atomically

  hipMemsetAsync(scalars, 0, NOUT * sizeof(float), stream);
  phi_kernel<<<BATCH / 64, 256, 0, stream>>>(x, W, bvec, Phi, s_row);
  out_kernel<<<BATCH / 64, 256, 0, stream>>>(Phi, Beta, s_row, out, scalars);
  sigma_kernel<<<4096, 256, 0, stream>>>(sig, scalars, sigma_out);
}

// Round 3
// 410.925 us; speedup vs baseline: 1.7410x; 1.7410x over previous
//
#include <hip/hip_runtime.h>
#include <math.h>

#define BATCH 16384
#define HIDDEN 2048
#define NOUT 256

static constexpr float PHI_SCALE = 0.08838834764831845f;  // sqrt(2/256)

typedef __attribute__((ext_vector_type(8))) short short8v;  // 8 bf16 = 4 VGPR
typedef __attribute__((ext_vector_type(4))) float f32x4;

#define MFMA16(a, b, c) __builtin_amdgcn_mfma_f32_16x16x32_bf16(a, b, c, 0, 0, 0)

// ---------------------------------------------------------------------------
// split_kernel: fp32 [R][2048] row-major -> hi/lo RTN-bf16 planes in
// fragment-native tiled layout: elem_off(r,k) = (r>>4)*32768 + (k>>3)*128
//                                             + (r&15)*8 + (k&7)
// chunk index idx = (r>>4)*4096 + kc*16 + (r&15)  ->  output elems idx*8..+8
// (consecutive lanes -> contiguous 16B output; reads 128B/row segments)
// ---------------------------------------------------------------------------
__device__ inline void split_rtn(float x, ushort& h, float& hf, ushort& l) {
  uint u = __float_as_uint(x);
  uint hb = (u + 0x7FFFu + ((u >> 16) & 1u)) >> 16;  // RTN-even to bf16
  h = (ushort)hb;
  hf = __uint_as_float(hb << 16);
  float lf = x - hf;                                  // exact in fp32
  uint u2 = __float_as_uint(lf);
  uint lb = (u2 + 0x7FFFu + ((u2 >> 16) & 1u)) >> 16;
  l = (ushort)lb;
}

__global__ __launch_bounds__(256) void split_kernel(
    const float* __restrict__ src, ushort* __restrict__ hi,
    ushort* __restrict__ lo, int nchunks)
{
  for (int idx = blockIdx.x * 256 + threadIdx.x; idx < nchunks;
       idx += gridDim.x * 256) {
    const int rhi = idx >> 12;
    const int kc  = (idx >> 4) & 255;
    const int rlo = idx & 15;
    const int r = rhi * 16 + rlo;
    const float4* s = (const float4*)&src[(size_t)r * HIDDEN + kc * 8];
    float4 v0 = s[0], v1 = s[1];
    const float* vp = (const float*)&v0;  // v0,v1 adjacent? copy to array:
    float vals[8] = {v0.x, v0.y, v0.z, v0.w, v1.x, v1.y, v1.z, v1.w};
    union { ushort us[8]; uint4 v; } H, L;
#pragma unroll
    for (int j = 0; j < 8; j++) {
      float hf;
      split_rtn(vals[j], H.us[j], hf, L.us[j]);
    }
    (void)vp;
    ((uint4*)hi)[idx] = H.v;
    ((uint4*)lo)[idx] = L.v;
  }
}

// ---------------------------------------------------------------------------
// phi_mfma: Phi = PHI_SCALE*cos((x@W^T) - b), s_row = row-sums of Phi.
// d = xh@wh^T + xh@wl^T + xl@wh^T via mfma_f32_16x16x32_bf16.
// Block: 64 rows x 256 cols, 4 waves (N-split, 64 cols each), 4x4 frags/wave.
// All fragments loaded directly from tiled global planes (L1/L2), no LDS GEMM.
// A-frag layout: lane holds row (l&15), k=(l>>4)*8+j  -> one dwordx4/lane.
// C/D layout: col = lane&15, row = (lane>>4)*4 + reg  [m89-verified].
// ---------------------------------------------------------------------------
__global__ __launch_bounds__(256) void phi_mfma(
    const ushort* __restrict__ Xh, const ushort* __restrict__ Xl,
    const ushort* __restrict__ Wh, const ushort* __restrict__ Wl,
    const float* __restrict__ bvec, float* Phi, float* __restrict__ s_row)
{
  __shared__ float srow_sh[64];
  const int tid  = threadIdx.x;
  const int wave = tid >> 6;
  const int lane = tid & 63;
  const int m0 = blockIdx.x * 64;

  if (tid < 64) srow_sh[tid] = 0.f;

  size_t aoff[4], boff[4];
#pragma unroll
  for (int f = 0; f < 4; ++f) {
    aoff[f] = (size_t)((m0 >> 4) + f) * 32768 + lane * 8;
    boff[f] = (size_t)(wave * 4 + f) * 32768 + lane * 8;
  }

  f32x4 acc[4][4];
#pragma unroll
  for (int m = 0; m < 4; ++m)
#pragma unroll
    for (int n = 0; n < 4; ++n) acc[m][n] = (f32x4){0.f, 0.f, 0.f, 0.f};

  short8v ah0[4], al0[4], bh0[4], bl0[4];
  short8v ah1[4], al1[4], bh1[4], bl1[4];

#define LD_SET(AH, AL, BH, BL, KO)                                   \
  do {                                                               \
    _Pragma("unroll") for (int f = 0; f < 4; ++f) {                  \
      AH[f] = *(const short8v*)&Xh[aoff[f] + (KO)];                  \
      AL[f] = *(const short8v*)&Xl[aoff[f] + (KO)];                  \
      BH[f] = *(const short8v*)&Wh[boff[f] + (KO)];                  \
      BL[f] = *(const short8v*)&Wl[boff[f] + (KO)];                  \
    }                                                                \
  } while (0)

#define MM_SET(AH, AL, BH, BL)                                       \
  do {                                                               \
    _Pragma("unroll") for (int m = 0; m < 4; ++m)                    \
    _Pragma("unroll") for (int n = 0; n < 4; ++n) {                  \
      acc[m][n] = MFMA16(AH[m], BH[n], acc[m][n]);                   \
      acc[m][n] = MFMA16(AH[m], BL[n], acc[m][n]);                   \
      acc[m][n] = MFMA16(AL[m], BH[n], acc[m][n]);                   \
    }                                                                \
  } while (0)

  // 64 K-steps of 32 (KO advances 512 elems = 4 chunks * 128), ping-pong.
  LD_SET(ah0, al0, bh0, bl0, 0);
  for (int p = 0; p < 31; ++p) {
    LD_SET(ah1, al1, bh1, bl1, (2 * p + 1) * 512);
    MM_SET(ah0, al0, bh0, bl0);
    LD_SET(ah0, al0, bh0, bl0, (2 * p + 2) * 512);
    MM_SET(ah1, al1, bh1, bl1);
  }
  LD_SET(ah1, al1, bh1, bl1, 63 * 512);
  MM_SET(ah0, al0, bh0, bl0);
  MM_SET(ah1, al1, bh1, bl1);

#undef LD_SET
#undef MM_SET

  __syncthreads();  // orders srow_sh init before atomics

  const int q  = lane >> 4;
  const int cl = lane & 15;
  float bv[4];
#pragma unroll
  for (int fn = 0; fn < 4; ++fn) bv[fn] = bvec[wave * 64 + fn * 16 + cl];

#pragma unroll
  for (int fm = 0; fm < 4; ++fm) {
#pragma unroll
    for (int i = 0; i < 4; ++i) {
      const int grow = m0 + fm * 16 + q * 4 + i;
      float rs = 0.f;
#pragma unroll
      for (int fn = 0; fn < 4; ++fn) {
        const int gcol = wave * 64 + fn * 16 + cl;
        const float ph = PHI_SCALE * __cosf(acc[fm][fn][i] - bv[fn]);
        rs += ph;
        Phi[(size_t)grow * NOUT + gcol] = ph;
      }
#pragma unroll
      for (int msk = 1; msk < 16; msk <<= 1) rs += __shfl_xor(rs, msk);
      if (cl == 0) atomicAdd(&srow_sh[fm * 16 + q * 4 + i], rs);
    }
  }
  __syncthreads();
  if (tid < 64) s_row[m0 + tid] = srow_sh[tid];
}

// ---------------------------------------------------------------------------
// Fallback fp32 phi (round-2 path, used only if ws too small)
// ---------------------------------------------------------------------------
__global__ __launch_bounds__(256) void phi_kernel(
    const float* __restrict__ x, const float* __restrict__ W,
    const float* __restrict__ bvec, float* __restrict__ Phi,
    float* __restrict__ s_row)
{
  __shared__ float xs[16][68];
  __shared__ float wsh[16][260];
  const int tid = threadIdx.x;
  const int tx = tid & 15;
  const int ty = tid >> 4;
  const int m0 = blockIdx.x * 64;
  const int lr = tid >> 2;
  const int lk = (tid & 3) * 4;
  float acc[4][16];
#pragma unroll
  for (int i = 0; i < 4; i++)
#pragma unroll
    for (int c = 0; c < 16; c++) acc[i][c] = 0.f;
  float4 xv  = *(const float4*)&x[(size_t)(m0 + lr) * HIDDEN + lk];
  float4 wv0 = *(const float4*)&W[(size_t)(lr      ) * HIDDEN + lk];
  float4 wv1 = *(const float4*)&W[(size_t)(lr +  64) * HIDDEN + lk];
  float4 wv2 = *(const float4*)&W[(size_t)(lr + 128) * HIDDEN + lk];
  float4 wv3 = *(const float4*)&W[(size_t)(lr + 192) * HIDDEN + lk];
  for (int kb = 0; kb < HIDDEN; kb += 16) {
    __syncthreads();
    {
      const float* xp = (const float*)&xv;
      const float* w0 = (const float*)&wv0;
      const float* w1 = (const float*)&wv1;
      const float* w2 = (const float*)&wv2;
      const float* w3 = (const float*)&wv3;
#pragma unroll
      for (int j = 0; j < 4; j++) {
        xs[lk + j][lr]        = xp[j];
        wsh[lk + j][lr]       = w0[j];
        wsh[lk + j][lr +  64] = w1[j];
        wsh[lk + j][lr + 128] = w2[j];
        wsh[lk + j][lr + 192] = w3[j];
      }
    }
    __syncthreads();
    if (kb + 16 < HIDDEN) {
      xv  = *(const float4*)&x[(size_t)(m0 + lr) * HIDDEN + kb + 16 + lk];
      wv0 = *(const float4*)&W[(size_t)(lr      ) * HIDDEN + kb + 16 + lk];
      wv1 = *(const float4*)&W[(size_t)(lr +  64) * HIDDEN + kb + 16 + lk];
      wv2 = *(const float4*)&W[(size_t)(lr + 128) * HIDDEN + kb + 16 + lk];
      wv3 = *(const float4*)&W[(size_t)(lr + 192) * HIDDEN + kb + 16 + lk];
    }
#pragma unroll
    for (int k = 0; k < 16; k++) {
      const float4 a = *(const float4*)&xs[k][ty * 4];
      const float* ap = (const float*)&a;
#pragma unroll
      for (int g = 0; g < 4; g++) {
        const float4 bb = *(const float4*)&wsh[k][tx * 4 + g * 64];
        const float* bp = (const float*)&bb;
#pragma unroll
        for (int i = 0; i < 4; i++)
#pragma unroll
          for (int j = 0; j < 4; j++)
            acc[i][g * 4 + j] = fmaf(ap[i], bp[j], acc[i][g * 4 + j]);
      }
    }
  }
  float rs[4] = {0.f, 0.f, 0.f, 0.f};
#pragma unroll
  for (int g = 0; g < 4; g++) {
    const int cbase = g * 64 + tx * 4;
    const float4 bb = *(const float4*)&bvec[cbase];
    const float* bp = (const float*)&bb;
#pragma unroll
    for (int i = 0; i < 4; i++) {
      float4 ph;
      float* pp = (float*)&ph;
#pragma unroll
      for (int j = 0; j < 4; j++) {
        pp[j] = PHI_SCALE * cosf(acc[i][g * 4 + j] - bp[j]);
        rs[i] += pp[j];
      }
      *(float4*)&Phi[(size_t)(m0 + ty * 4 + i) * NOUT + cbase] = ph;
    }
  }
#pragma unroll
  for (int i = 0; i < 4; i++) {
    float v = rs[i];
#pragma unroll
    for (int m = 1; m < 16; m <<= 1) v += __shfl_xor(v, m);
    if (tx == 0) s_row[m0 + ty * 4 + i] = v;
  }
}

// ---------------------------------------------------------------------------
// out_kernel: out = Phi @ Beta; softmax; scalars[k] += sum_b w[b,k]*s2[b].
// NOTE: Phi may alias out (in-place); restrict removed on those params.
// ---------------------------------------------------------------------------
__global__ __launch_bounds__(256) void out_kernel(
    const float* Phi, const float* __restrict__ Beta,
    const float* __restrict__ s_row, float* out,
    float* __restrict__ scalars)
{
  __shared__ float ps[16][68];
  __shared__ float bs[16][260];
  __shared__ float sb[NOUT];

  const int tid = threadIdx.x;
  const int tx = tid & 15;
  const int ty = tid >> 4;
  const int m0 = blockIdx.x * 64;
  const int lr = tid >> 2;
  const int lk = (tid & 3) * 4;
  const int bkr = tid >> 4;
  const int bc = (tid & 15) * 16;

  sb[tid] = 0.f;

  float acc[4][16];
#pragma unroll
  for (int i = 0; i < 4; i++)
#pragma unroll
    for (int c = 0; c < 16; c++) acc[i][c] = 0.f;

  float4 pv  = *(const float4*)&Phi[(size_t)(m0 + lr) * NOUT + lk];
  float4 bv0 = *(const float4*)&Beta[(size_t)bkr * NOUT + bc];
  float4 bv1 = *(const float4*)&Beta[(size_t)bkr * NOUT + bc + 4];
  float4 bv2 = *(const float4*)&Beta[(size_t)bkr * NOUT + bc + 8];
  float4 bv3 = *(const float4*)&Beta[(size_t)bkr * NOUT + bc + 12];

  for (int kb = 0; kb < NOUT; kb += 16) {
    __syncthreads();
    {
      const float* pp = (const float*)&pv;
#pragma unroll
      for (int j = 0; j < 4; j++) ps[lk + j][lr] = pp[j];
      *(float4*)&bs[bkr][bc]      = bv0;
      *(float4*)&bs[bkr][bc + 4]  = bv1;
      *(float4*)&bs[bkr][bc + 8]  = bv2;
      *(float4*)&bs[bkr][bc + 12] = bv3;
    }
    __syncthreads();
    if (kb + 16 < NOUT) {
      pv  = *(const float4*)&Phi[(size_t)(m0 + lr) * NOUT + kb + 16 + lk];
      bv0 = *(const float4*)&Beta[(size_t)(kb + 16 + bkr) * NOUT + bc];
      bv1 = *(const float4*)&Beta[(size_t)(kb + 16 + bkr) * NOUT + bc + 4];
      bv2 = *(const float4*)&Beta[(size_t)(kb + 16 + bkr) * NOUT + bc + 8];
      bv3 = *(const float4*)&Beta[(size_t)(kb + 16 + bkr) * NOUT + bc + 12];
    }
#pragma unroll
    for (int k = 0; k < 16; k++) {
      const float4 a = *(const float4*)&ps[k][ty * 4];
      const float* ap = (const float*)&a;
#pragma unroll
      for (int g = 0; g < 4; g++) {
        const float4 bb = *(const float4*)&bs[k][tx * 4 + g * 64];
        const float* bp = (const float*)&bb;
#pragma unroll
        for (int i = 0; i < 4; i++)
#pragma unroll
          for (int j = 0; j < 4; j++)
            acc[i][g * 4 + j] = fmaf(ap[i], bp[j], acc[i][g * 4 + j]);
      }
    }
  }

#pragma unroll
  for (int g = 0; g < 4; g++) {
    const int cbase = g * 64 + tx * 4;
#pragma unroll
    for (int i = 0; i < 4; i++) {
      float4 ov;
      ov.x = acc[i][g * 4 + 0]; ov.y = acc[i][g * 4 + 1];
      ov.z = acc[i][g * 4 + 2]; ov.w = acc[i][g * 4 + 3];
      *(float4*)&out[(size_t)(m0 + ty * 4 + i) * NOUT + cbase] = ov;
    }
  }

  float cp[16];
#pragma unroll
  for (int c = 0; c < 16; c++) cp[c] = 0.f;

#pragma unroll
  for (int i = 0; i < 4; i++) {
    float mx = acc[i][0];
#pragma unroll
    for (int c = 1; c < 16; c++) mx = fmaxf(mx, acc[i][c]);
#pragma unroll
    for (int m = 1; m < 16; m <<= 1) mx = fmaxf(mx, __shfl_xor(mx, m));
    float e[16];
    float sum = 0.f;
#pragma unroll
    for (int c = 0; c < 16; c++) { e[c] = __expf(acc[i][c] - mx); sum += e[c]; }
#pragma unroll
    for (int m = 1; m < 16; m <<= 1) sum += __shfl_xor(sum, m);
    const float inv = 1.f / sum;
    float sv = s_row[m0 + ty * 4 + i];
    sv = sv * sv;
#pragma unroll
    for (int c = 0; c < 16; c++) {
      const float p = e[c] * inv;
      cp[c] = fmaf(p * (1.f - p), sv, cp[c]);
    }
  }
#pragma unroll
  for (int c = 0; c < 16; c++) {
    cp[c] += __shfl_xor(cp[c], 16);
    cp[c] += __shfl_xor(cp[c], 32);
  }
  if ((ty & 3) == 0) {
#pragma unroll
    for (int g = 0; g < 4; g++)
#pragma unroll
      for (int j = 0; j < 4; j++)
        atomicAdd(&sb[g * 64 + tx * 4 + j], cp[g * 4 + j]);
  }
  __syncthreads();
  atomicAdd(&scalars[tid], sb[tid]);
}

// ---------------------------------------------------------------------------
// sigma_kernel: sigma_new = 0.999*sigma + (0.001/65536)*scalars[k]
// ---------------------------------------------------------------------------
__global__ __launch_bounds__(256) void sigma_kernel(
    const float* __restrict__ sig, const float* __restrict__ scalars,
    float* __restrict__ so)
{
  const int total4 = (NOUT * NOUT * NOUT) / 4;
  const float cscale = 0.001f / 65536.f;
  for (int i = blockIdx.x * 256 + threadIdx.x; i < total4; i += gridDim.x * 256) {
    const float4 s = ((const float4*)sig)[i];
    const int k = i >> 14;
    const float add = scalars[k] * cscale;
    float4 r;
    r.x = fmaf(0.999f, s.x, add);
    r.y = fmaf(0.999f, s.y, add);
    r.z = fmaf(0.999f, s.z, add);
    r.w = fmaf(0.999f, s.w, add);
    ((float4*)so)[i] = r;
  }
}

extern "C" void kernel_launch(void* const* d_in, const int* in_sizes, int n_in,
                              void* d_out, int out_size, void* d_ws, size_t ws_size,
                              hipStream_t stream)
{
  const float* x    = (const float*)d_in[0];
  const float* W    = (const float*)d_in[1];
  const float* bvec = (const float*)d_in[2];
  const float* Beta = (const float*)d_in[3];
  const float* sig  = (const float*)d_in[4];

  float* out = (float*)d_out;
  float* sigma_out = out + (size_t)BATCH * NOUT;

  const size_t XE = (size_t)BATCH * HIDDEN;  // 33.5M elems
  const size_t WE = (size_t)NOUT * HIDDEN;   // 524288 elems
  const size_t need = XE * 2 + WE * 2 * 2 + (BATCH + NOUT) * 4 + 4096;

  if (ws_size >= need) {
    ushort* Xh = (ushort*)d_ws;
    ushort* Wh = Xh + XE;
    ushort* Wl = Wh + WE;
    float* s_row   = (float*)(Wl + WE);
    float* scalars = s_row + BATCH;
    ushort* Xl = (ushort*)sigma_out;  // borrowed; overwritten by sigma_kernel
    float* Phi = out;                 // in-place with out (row-partitioned)

    hipMemsetAsync(scalars, 0, NOUT * sizeof(float), stream);
    split_kernel<<<256, 256, 0, stream>>>(W, Wh, Wl, NOUT * 256);
    split_kernel<<<2048, 256, 0, stream>>>(x, Xh, Xl, BATCH * 256);
    phi_mfma<<<BATCH / 64, 256, 0, stream>>>(Xh, Xl, Wh, Wl, bvec, Phi, s_row);
    out_kernel<<<BATCH / 64, 256, 0, stream>>>(Phi, Beta, s_row, out, scalars);
    sigma_kernel<<<4096, 256, 0, stream>>>(sig, scalars, sigma_out);
  } else {
    // fallback: round-2 fp32 path
    float* Phi = sigma_out;
    float* s_row   = (float*)d_ws;
    float* scalars = s_row + BATCH;
    hipMemsetAsync(scalars, 0, NOUT * sizeof(float), stream);
    phi_kernel<<<BATCH / 64, 256, 0, stream>>>(x, W, bvec, Phi, s_row);
    out_kernel<<<BATCH / 64, 256, 0, stream>>>(Phi, Beta, s_row, out, scalars);
    sigma_kernel<<<4096, 256, 0, stream>>>(sig, scalars, sigma_out);
  }
}

// Round 4
// 345.498 us; speedup vs baseline: 2.0707x; 1.1894x over previous
//
#include <hip/hip_runtime.h>
#include <math.h>

#define BATCH 16384
#define HIDDEN 2048
#define NOUT 256

static constexpr float PHI_SCALE = 0.08838834764831845f;  // sqrt(2/256)

typedef __attribute__((ext_vector_type(8))) short short8v;  // 8 bf16 = 4 VGPR
typedef __attribute__((ext_vector_type(4))) float f32x4;

#define MFMA16(a, b, c) __builtin_amdgcn_mfma_f32_16x16x32_bf16(a, b, c, 0, 0, 0)

// pack high-16s of two fp32 words: result = (u1.hi16 << 16) | u0.hi16
__device__ __forceinline__ uint pack_hi16(uint u0, uint u1) {
  return __builtin_amdgcn_perm(u1, u0, 0x07060302);
}

// truncate-split one A fragment (8 fp32) into hi/lo bf16 fragments.
// hi = trunc(x); lo = trunc(x - hi)  (residual exact in fp32; only lo's
// rounding matters => total dropped error ~2^-16 per term)
__device__ __forceinline__ void split_frag(float4 v0, float4 v1,
                                           short8v& hh, short8v& ll) {
  float fv[8] = {v0.x, v0.y, v0.z, v0.w, v1.x, v1.y, v1.z, v1.w};
  uint hu[8];
  uint lu[8];
#pragma unroll
  for (int j = 0; j < 8; j++) {
    uint u = __float_as_uint(fv[j]);
    hu[j] = u;
    float hf = __uint_as_float(u & 0xFFFF0000u);
    lu[j] = __float_as_uint(fv[j] - hf);
  }
  union { uint u[4]; short8v s; } H, L;
#pragma unroll
  for (int j = 0; j < 4; j++) {
    H.u[j] = pack_hi16(hu[2 * j], hu[2 * j + 1]);
    L.u[j] = pack_hi16(lu[2 * j], lu[2 * j + 1]);
  }
  hh = H.s;
  ll = L.s;
}

// ---------------------------------------------------------------------------
// split_kernel (W): fp32 [256][2048] -> hi/lo RTN-bf16 tiled planes
// elem_off(r,k) = (r>>4)*32768 + (k>>3)*128 + (r&15)*8 + (k&7)
// ---------------------------------------------------------------------------
__device__ __forceinline__ void split_rtn(float x, ushort& h, ushort& l) {
  uint u = __float_as_uint(x);
  uint hb = (u + 0x7FFFu + ((u >> 16) & 1u)) >> 16;
  h = (ushort)hb;
  float hf = __uint_as_float(hb << 16);
  float lf = x - hf;
  uint u2 = __float_as_uint(lf);
  l = (ushort)((u2 + 0x7FFFu + ((u2 >> 16) & 1u)) >> 16);
}

__global__ __launch_bounds__(256) void split_kernel(
    const float* __restrict__ src, ushort* __restrict__ hi,
    ushort* __restrict__ lo, int nchunks)
{
  for (int idx = blockIdx.x * 256 + threadIdx.x; idx < nchunks;
       idx += gridDim.x * 256) {
    const int rhi = idx >> 12;
    const int kc  = (idx >> 4) & 255;
    const int rlo = idx & 15;
    const int r = rhi * 16 + rlo;
    const float4* s = (const float4*)&src[(size_t)r * HIDDEN + kc * 8];
    float4 v0 = s[0], v1 = s[1];
    float vals[8] = {v0.x, v0.y, v0.z, v0.w, v1.x, v1.y, v1.z, v1.w};
    union { ushort us[8]; uint4 v; } H, L;
#pragma unroll
    for (int j = 0; j < 8; j++) split_rtn(vals[j], H.us[j], L.us[j]);
    ((uint4*)hi)[idx] = H.v;
    ((uint4*)lo)[idx] = L.v;
  }
}

// ---------------------------------------------------------------------------
// btile_kernel: Bt[n][k] (tiled bf16) = Beta[k][n]  (transposed B-plane for
// GEMM2: out = Phi @ Beta needs B-frag elems Beta[k][n] at col=n)
// ---------------------------------------------------------------------------
__global__ __launch_bounds__(256) void btile_kernel(
    const float* __restrict__ Beta, ushort* __restrict__ Bt)
{
  const int idx = blockIdx.x * 256 + threadIdx.x;  // 8192 = 256 n * 32 kc
  const int n = idx >> 5;
  const int kc = idx & 31;
  union { ushort us[8]; uint4 v; } P;
#pragma unroll
  for (int j = 0; j < 8; j++) {
    float v = Beta[(size_t)(kc * 8 + j) * NOUT + n];
    uint u = __float_as_uint(v);
    P.us[j] = (ushort)((u + 0x7FFFu + ((u >> 16) & 1u)) >> 16);
  }
  *(uint4*)&Bt[(size_t)(n >> 4) * 4096 + kc * 128 + (n & 15) * 8] = P.v;
}

// ---------------------------------------------------------------------------
// mega_kernel: per 64-row block:
//  GEMM1: d = x@W^T (bf16x2 truncate-split, 3 MFMA passes), B LDS-dbuf staged
//  Phi = PHI_SCALE*cos(d - b) -> swizzled bf16 LDS tile + row-sums
//  GEMM2: out = Phi @ Beta (bf16 MFMA, A from LDS, B from tiled global)
//  softmax + w*s2 class partials -> global scalars atomics
// 8 waves: wm(2) x wn(4); wave tile 32 rows x 64 cols; 2x4 frags.
// ---------------------------------------------------------------------------
__global__ __launch_bounds__(512, 2) void mega_kernel(
    const float* __restrict__ x, const ushort* __restrict__ Wh,
    const ushort* __restrict__ Wl, const ushort* __restrict__ Bt,
    const float* __restrict__ bvec, float* __restrict__ out,
    float* __restrict__ scalars)
{
  __shared__ ushort bsmem[2][2][16][512];  // [buf][plane][rb][elem] 64 KB
  __shared__ ushort phis[64 * 256];        // 32 KB, XOR-swizzled
  __shared__ float srow[64];
  __shared__ float pmax[4][64];
  __shared__ float psum[4][64];
  __shared__ float sb[NOUT];

  const int tid = threadIdx.x;
  const int wave = tid >> 6, lane = tid & 63;
  const int wm = wave >> 2, wn = wave & 3;
  const int q = lane >> 4, c = lane & 15;
  const int wn4 = wn * 4;
  const int m0 = blockIdx.x * 64;

  if (tid < 64) srow[tid] = 0.f;
  if (tid < NOUT) sb[tid] = 0.f;

  const float* xrow0 = x + (size_t)(m0 + wm * 32 + c) * HIDDEN + q * 8;
  const float* xrow1 = xrow0 + (size_t)16 * HIDDEN;

  f32x4 acc[2][4];
#pragma unroll
  for (int fm = 0; fm < 2; fm++)
#pragma unroll
    for (int fn = 0; fn < 4; fn++) acc[fm][fn] = (f32x4){0.f, 0.f, 0.f, 0.f};

  uint4 sreg[4];
  float4 A0a0, A0b0, A0a1, A0b1, A1a0, A1b0, A1a1, A1b1;

#define STAGE_LOAD(KK)                                                     \
  do {                                                                     \
    _Pragma("unroll") for (int i_ = 0; i_ < 4; i_++) {                     \
      const int seg = wave + i_ * 8;                                       \
      const ushort* sp = (seg & 16) ? Wl : Wh;                             \
      sreg[i_] = *(const uint4*)&sp[(size_t)(seg & 15) * 32768 +           \
                                    (size_t)(KK) * 512 + lane * 8];        \
    }                                                                      \
  } while (0)

#define STAGE_WRITE(BUF)                                                   \
  do {                                                                     \
    _Pragma("unroll") for (int i_ = 0; i_ < 4; i_++) {                     \
      const int seg = wave + i_ * 8;                                       \
      *(uint4*)&bsmem[BUF][(seg >> 4) & 1][seg & 15][lane * 8] = sreg[i_]; \
    }                                                                      \
  } while (0)

#define ALOAD(Pa0, Pb0, Pa1, Pb1, KK)                                      \
  do {                                                                     \
    Pa0 = *(const float4*)(xrow0 + (size_t)(KK) * 32);                     \
    Pb0 = *(const float4*)(xrow0 + (size_t)(KK) * 32 + 4);                 \
    Pa1 = *(const float4*)(xrow1 + (size_t)(KK) * 32);                     \
    Pb1 = *(const float4*)(xrow1 + (size_t)(KK) * 32 + 4);                 \
  } while (0)

#define COMPUTE(Pa0, Pb0, Pa1, Pb1, BUF)                                   \
  do {                                                                     \
    short8v bh_[4], bl_[4], ah_[2], al_[2];                                \
    _Pragma("unroll") for (int fn_ = 0; fn_ < 4; fn_++) {                  \
      bh_[fn_] = *(short8v*)&bsmem[BUF][0][wn4 + fn_][lane * 8];           \
      bl_[fn_] = *(short8v*)&bsmem[BUF][1][wn4 + fn_][lane * 8];           \
    }                                                                      \
    split_frag(Pa0, Pb0, ah_[0], al_[0]);                                  \
    split_frag(Pa1, Pb1, ah_[1], al_[1]);                                  \
    _Pragma("unroll") for (int fm_ = 0; fm_ < 2; fm_++)                    \
    _Pragma("unroll") for (int fn_ = 0; fn_ < 4; fn_++) {                  \
      acc[fm_][fn_] = MFMA16(ah_[fm_], bh_[fn_], acc[fm_][fn_]);           \
      acc[fm_][fn_] = MFMA16(ah_[fm_], bl_[fn_], acc[fm_][fn_]);           \
      acc[fm_][fn_] = MFMA16(al_[fm_], bh_[fn_], acc[fm_][fn_]);           \
    }                                                                      \
  } while (0)

  // prologue
  ALOAD(A0a0, A0b0, A0a1, A0b1, 0);
  STAGE_LOAD(0);
  STAGE_WRITE(0);

  for (int p = 0; p < 32; ++p) {
    const int k0 = 2 * p;
    __syncthreads();
    // stage k0+1 (always exists: k0 <= 62), prefetch A(k0+1)
    STAGE_LOAD(k0 + 1);
    ALOAD(A1a0, A1b0, A1a1, A1b1, k0 + 1);
    COMPUTE(A0a0, A0b0, A0a1, A0b1, 0);
    STAGE_WRITE(1);
    __syncthreads();
    if (k0 + 2 < 64) {
      STAGE_LOAD(k0 + 2);
      ALOAD(A0a0, A0b0, A0a1, A0b1, k0 + 2);
    }
    COMPUTE(A1a0, A1b0, A1a1, A1b1, 1);
    if (k0 + 2 < 64) STAGE_WRITE(0);
  }

#undef STAGE_LOAD
#undef STAGE_WRITE
#undef ALOAD
#undef COMPUTE

  // ---- epilogue 1: Phi = scale*cos(d - b) -> swizzled bf16 LDS + row sums
  {
    float bv[4];
#pragma unroll
    for (int fn = 0; fn < 4; fn++) bv[fn] = bvec[wn * 64 + fn * 16 + c];
#pragma unroll
    for (int fm = 0; fm < 2; fm++) {
#pragma unroll
      for (int i = 0; i < 4; i++) {
        const int row = wm * 32 + fm * 16 + q * 4 + i;
        float rs = 0.f;
#pragma unroll
        for (int fn = 0; fn < 4; fn++) {
          const float ph = PHI_SCALE * __cosf(acc[fm][fn][i] - bv[fn]);
          rs += ph;
          uint u = __float_as_uint(ph);
          ushort pb = (ushort)((u + 0x7FFFu + ((u >> 16) & 1u)) >> 16);
          const int col = wn * 64 + fn * 16 + c;
          const int byte = (row * 512 + col * 2) ^ ((row & 7) << 4);
          *(ushort*)((char*)phis + byte) = pb;
        }
#pragma unroll
        for (int msk = 1; msk < 16; msk <<= 1) rs += __shfl_xor(rs, msk);
        if (c == 0) atomicAdd(&srow[row], rs);
      }
    }
  }
  __syncthreads();

  // ---- GEMM2: out = Phi(bf16,LDS) @ Beta(bf16 tiled global), K=256
  f32x4 acc2[2][4];
#pragma unroll
  for (int fm = 0; fm < 2; fm++)
#pragma unroll
    for (int fn = 0; fn < 4; fn++) acc2[fm][fn] = (f32x4){0.f, 0.f, 0.f, 0.f};

#pragma unroll
  for (int kk = 0; kk < 8; ++kk) {
    short8v pa[2], bt[4];
#pragma unroll
    for (int fm = 0; fm < 2; fm++) {
      const int row = wm * 32 + fm * 16 + c;  // A-frag: lane row = lane&15
      const int byte = (row * 512 + kk * 64 + q * 16) ^ ((row & 7) << 4);
      pa[fm] = *(short8v*)((char*)phis + byte);
    }
#pragma unroll
    for (int fn = 0; fn < 4; fn++)
      bt[fn] = *(const short8v*)&Bt[(size_t)(wn4 + fn) * 4096 + kk * 512 +
                                    lane * 8];
#pragma unroll
    for (int fm = 0; fm < 2; fm++)
#pragma unroll
      for (int fn = 0; fn < 4; fn++)
        acc2[fm][fn] = MFMA16(pa[fm], bt[fn], acc2[fm][fn]);
  }

  // ---- epilogue 2: out write + softmax + class partials
  // partial row-max over this wave's 64 cols
#pragma unroll
  for (int fm = 0; fm < 2; fm++) {
#pragma unroll
    for (int i = 0; i < 4; i++) {
      const int row = wm * 32 + fm * 16 + q * 4 + i;
      float mx = acc2[fm][0][i];
#pragma unroll
      for (int fn = 1; fn < 4; fn++) mx = fmaxf(mx, acc2[fm][fn][i]);
#pragma unroll
      for (int msk = 1; msk < 16; msk <<= 1) mx = fmaxf(mx, __shfl_xor(mx, msk));
      if (c == 0) pmax[wn][row] = mx;
    }
  }
  __syncthreads();

  float ev[2][4][4];
  float rminv[2][4];  // holds global row max, then 1/denom
#pragma unroll
  for (int fm = 0; fm < 2; fm++) {
#pragma unroll
    for (int i = 0; i < 4; i++) {
      const int row = wm * 32 + fm * 16 + q * 4 + i;
      float rm = fmaxf(fmaxf(pmax[0][row], pmax[1][row]),
                       fmaxf(pmax[2][row], pmax[3][row]));
      float s = 0.f;
#pragma unroll
      for (int fn = 0; fn < 4; fn++) {
        const float e = __expf(acc2[fm][fn][i] - rm);
        ev[fm][fn][i] = e;
        s += e;
      }
#pragma unroll
      for (int msk = 1; msk < 16; msk <<= 1) s += __shfl_xor(s, msk);
      if (c == 0) psum[wn][row] = s;
    }
  }
  __syncthreads();

  // write out (raw logits) + accumulate cp
  float cp[4] = {0.f, 0.f, 0.f, 0.f};
#pragma unroll
  for (int fm = 0; fm < 2; fm++) {
#pragma unroll
    for (int i = 0; i < 4; i++) {
      const int row = wm * 32 + fm * 16 + q * 4 + i;
      const float inv =
          1.f / (psum[0][row] + psum[1][row] + psum[2][row] + psum[3][row]);
      const float sv = srow[row];
      const float s2 = sv * sv;
#pragma unroll
      for (int fn = 0; fn < 4; fn++) {
        const int col = wn * 64 + fn * 16 + c;
        out[(size_t)(m0 + row) * NOUT + col] = acc2[fm][fn][i];
        const float pr = ev[fm][fn][i] * inv;
        cp[fn] = fmaf(pr * (1.f - pr), s2, cp[fn]);
      }
    }
  }
#pragma unroll
  for (int fn = 0; fn < 4; fn++) {
    cp[fn] += __shfl_xor(cp[fn], 16);
    cp[fn] += __shfl_xor(cp[fn], 32);
  }
  if (lane < 16) {
#pragma unroll
    for (int fn = 0; fn < 4; fn++) atomicAdd(&sb[wn * 64 + fn * 16 + c], cp[fn]);
  }
  __syncthreads();
  if (tid < NOUT) atomicAdd(&scalars[tid], sb[tid]);
}

// ---------------------------------------------------------------------------
// sigma_kernel: sigma_new = 0.999*sigma + (0.001/65536)*scalars[k]
// ---------------------------------------------------------------------------
__global__ __launch_bounds__(256) void sigma_kernel(
    const float* __restrict__ sig, const float* __restrict__ scalars,
    float* __restrict__ so)
{
  const int total4 = (NOUT * NOUT * NOUT) / 4;
  const float cscale = 0.001f / 65536.f;
  for (int i = blockIdx.x * 256 + threadIdx.x; i < total4; i += gridDim.x * 256) {
    const float4 s = ((const float4*)sig)[i];
    const int k = i >> 14;
    const float add = scalars[k] * cscale;
    float4 r;
    r.x = fmaf(0.999f, s.x, add);
    r.y = fmaf(0.999f, s.y, add);
    r.z = fmaf(0.999f, s.z, add);
    r.w = fmaf(0.999f, s.w, add);
    ((float4*)so)[i] = r;
  }
}

extern "C" void kernel_launch(void* const* d_in, const int* in_sizes, int n_in,
                              void* d_out, int out_size, void* d_ws, size_t ws_size,
                              hipStream_t stream)
{
  const float* x    = (const float*)d_in[0];
  const float* W    = (const float*)d_in[1];
  const float* bvec = (const float*)d_in[2];
  const float* Beta = (const float*)d_in[3];
  const float* sig  = (const float*)d_in[4];

  float* out = (float*)d_out;
  float* sigma_out = out + (size_t)BATCH * NOUT;

  const size_t WE = (size_t)NOUT * HIDDEN;  // 524288
  ushort* Wh = (ushort*)d_ws;
  ushort* Wl = Wh + WE;
  ushort* Bt = Wl + WE;
  float* scalars = (float*)(Bt + (size_t)NOUT * NOUT);

  hipMemsetAsync(scalars, 0, NOUT * sizeof(float), stream);
  split_kernel<<<256, 256, 0, stream>>>(W, Wh, Wl, NOUT * 256);
  btile_kernel<<<32, 256, 0, stream>>>(Beta, Bt);
  mega_kernel<<<BATCH / 64, 512, 0, stream>>>(x, Wh, Wl, Bt, bvec, out, scalars);
  sigma_kernel<<<4096, 256, 0, stream>>>(sig, scalars, sigma_out);
}